// Round 8
// baseline (82.557 us; speedup 1.0000x reference)
//
#include <hip/hip_runtime.h>
#include <hip/hip_bf16.h>

typedef __attribute__((ext_vector_type(8))) short bf16x8;
typedef __attribute__((ext_vector_type(4))) float f32x4;

#define B_ROWS 8192
#define NROWS 16384             // 2B
#define D 128
#define C1 2.8853900817779268f  // 2*log2(e)  (sim = 2*cos; exp(x)=2^(x*log2e))
#define E_M2 0.13533528323661270f // exp(-2) == 2^(-C1): the folded row-max shift
#define RSCALE 1.6986436f       // sqrt(C1), folded into reps on both operands
#define NSPLIT 16               // col-tile stride per row-chunk
#define NCHUNK 64               // 256-row chunks
#define TILE_COLS 64
#define TILE_BYTES (TILE_COLS * D * 2) // 16 KB per buffer

// Raw hardware exp2/log2: args are bounded, no range handling needed.
__device__ __forceinline__ float fast_exp2(float x) {
#if __has_builtin(__builtin_amdgcn_exp2f)
    return __builtin_amdgcn_exp2f(x);
#else
    float r; asm("v_exp_f32 %0, %1" : "=v"(r) : "v"(x)); return r;
#endif
}
__device__ __forceinline__ float fast_log2(float x) {
#if __has_builtin(__builtin_amdgcn_logf)
    return __builtin_amdgcn_logf(x);
#else
    float r; asm("v_log_f32 %0, %1" : "=v"(r) : "v"(x)); return r;
#endif
}

__device__ __forceinline__ unsigned short f2bf(float f) {
    union { float f; unsigned u; } v; v.f = f;
    unsigned r = v.u + 0x7FFFu + ((v.u >> 16) & 1u); // RNE
    return (unsigned short)(r >> 16);
}

// K1: row norms + positive dots + bf16 reps (pre-scaled by sqrt(C1)).
__global__ __launch_bounds__(256) void k_norm(const float* __restrict__ zi,
                                              const float* __restrict__ zj,
                                              unsigned* __restrict__ repsU,
                                              float* __restrict__ pos) {
    int w = threadIdx.x >> 6, lane = threadIdx.x & 63;
    int row = blockIdx.x * 4 + w;
    const float2* a2 = (const float2*)(zi + (size_t)row * D);
    const float2* b2 = (const float2*)(zj + (size_t)row * D);
    float2 a = a2[lane], b = b2[lane];
    float si = a.x * a.x + a.y * a.y;
    float sj = b.x * b.x + b.y * b.y;
    float sd = a.x * b.x + a.y * b.y;
#pragma unroll
    for (int m = 32; m; m >>= 1) {
        si += __shfl_xor(si, m);
        sj += __shfl_xor(sj, m);
        sd += __shfl_xor(sd, m);
    }
    float inv_i = 1.0f / fmaxf(sqrtf(si), 1e-12f);
    float inv_j = 1.0f / fmaxf(sqrtf(sj), 1e-12f);
    float sa = inv_i * RSCALE, sb = inv_j * RSCALE;
    repsU[(size_t)row * 64 + lane] =
        (unsigned)f2bf(a.x * sa) | ((unsigned)f2bf(a.y * sa) << 16);
    repsU[(size_t)(row + B_ROWS) * 64 + lane] =
        (unsigned)f2bf(b.x * sb) | ((unsigned)f2bf(b.y * sb) << 16);
    if (lane == 0) pos[row] = fast_exp2(sd * inv_i * inv_j * C1); // exp(2*cos_ij)
}

// K2: symmetric-half fused sim-GEMM + exp + row/col sums.
// Block (I, s): rows [256I, 256I+256), col-tiles j = jstart + 16t (j >= 4I).
// Off-diagonal-block tiles (colBase >= rowBase+256) also emit column sums
// (= transposed rows' neg-sums) via csum -> lk-shuffle -> colredL LDS ->
// one wave stores 64 floats to colpart[I][col] (unique writer, deterministic).
// Diagonal 256x256 block computed in full with self-mask, row-sums only.
// C/D layout (m89-verified): row=(lane>>4)*4+q, col=lane&15.
__global__ __launch_bounds__(256, 2) void k_negsum(const unsigned short* __restrict__ R,
                                                   float* __restrict__ rowpart,
                                                   float* __restrict__ colpart) {
    __shared__ char smem[2][TILE_BYTES];
    __shared__ float colredL[2][4][64];
    int I = blockIdx.x >> 4;                // row chunk; heavy (small I) dispatch first
    int s = blockIdx.x & (NSPLIT - 1);
    int rowBase = I << 8;
    int w = threadIdx.x >> 6;
    int lane = threadIdx.x & 63;
    int lr = lane & 15, lk = lane >> 4;
    int waveRow = rowBase + w * 64;

    bf16x8 afrag[4][4];
#pragma unroll
    for (int r = 0; r < 4; ++r)
#pragma unroll
        for (int kk = 0; kk < 4; ++kk)
            afrag[r][kk] = *(const bf16x8*)(R + (size_t)(waveRow + r * 16 + lr) * D + kk * 32 + lk * 8);

    // staging: instruction j of wave w covers dest bytes (w*4+j)*1024 + lane*16
    int srcoff[4], dstoff[4];
#pragma unroll
    for (int j = 0; j < 4; ++j) {
        int o = (w * 4 + j) * 1024 + lane * 16;
        int row = o >> 8, c = o & 255;
        srcoff[j] = row * 256 + (c ^ ((row & 7) << 4)); // pre-swizzled global source
        dstoff[j] = (w * 4 + j) * 1024;                 // wave-uniform LDS base
    }

    // tile list: j = jstart + 16t, j in [4I, 256)
    int dph = (s - ((I << 2) & 15)) & 15;
    int jstart = (I << 2) + dph;
    int nt = (jstart < 256) ? (((255 - jstart) >> 4) + 1) : 0;

    const char* Rb = (const char*)R;

    // swizzled read-offset components: lds_off(ct,kk) = ct*4096 + lbase + (kk*64 ^ m64)
    int m64 = (lr & 4) << 4;
    int lbase = lr * 256 + ((lk * 16) ^ ((lr & 3) << 4));

    float acc[4][4] = {};

#define STAGE(buf, jj)                                                            \
    do {                                                                          \
        const char* tb_ = Rb + (size_t)(jj) * (TILE_COLS * 256);                  \
        _Pragma("unroll")                                                         \
        for (int j = 0; j < 4; ++j)                                               \
            __builtin_amdgcn_global_load_lds(                                     \
                (const __attribute__((address_space(1))) unsigned*)(tb_ + srcoff[j]), \
                (__attribute__((address_space(3))) unsigned*)(&smem[buf][dstoff[j]]), \
                16, 0, 0);                                                        \
    } while (0)

#define BATCH_BODY(DIAG)                                                          \
    do {                                                                          \
        _Pragma("unroll")                                                         \
        for (int ct = 0; ct < 4; ++ct) {                                          \
            _Pragma("unroll")                                                     \
            for (int r = 0; r < 4; ++r) {                                         \
                f32x4 c = {0.f, 0.f, 0.f, 0.f};                                   \
                c = __builtin_amdgcn_mfma_f32_16x16x32_bf16(afrag[r][0], bf[ct][0], c, 0, 0, 0); \
                c = __builtin_amdgcn_mfma_f32_16x16x32_bf16(afrag[r][1], bf[ct][1], c, 0, 0, 0); \
                c = __builtin_amdgcn_mfma_f32_16x16x32_bf16(afrag[r][2], bf[ct][2], c, 0, 0, 0); \
                c = __builtin_amdgcn_mfma_f32_16x16x32_bf16(afrag[r][3], bf[ct][3], c, 0, 0, 0); \
                if (DIAG && ct == r) {                                            \
                    _Pragma("unroll")                                             \
                    for (int q = 0; q < 4; ++q)                                   \
                        if (lk * 4 + q != lr) {                                   \
                            float e = fast_exp2(c[q]);                            \
                            acc[r][q] += e; csum[ct] += e;                        \
                        }                                                         \
                } else {                                                          \
                    _Pragma("unroll")                                             \
                    for (int q = 0; q < 4; ++q) {                                 \
                        float e = fast_exp2(c[q]);                                \
                        acc[r][q] += e; csum[ct] += e;                            \
                    }                                                             \
                }                                                                 \
            }                                                                     \
        }                                                                         \
    } while (0)

    if (nt > 0) STAGE(0, jstart);
    __syncthreads();                         // drains vmcnt(0) before first reads
    int cur = 0;
    int prevColBase = -1, prevBuf = 0;
    for (int t = 0; t < nt; ++t) {
        int jt = jstart + (t << 4);
        int colBase = jt << 6;
        // store previous off-diag tile's column partials (one rotating wave)
        if (prevColBase >= 0 && w == ((t + 3) & 3)) {
            float v = colredL[prevBuf][0][lane] + colredL[prevBuf][1][lane] +
                      colredL[prevBuf][2][lane] + colredL[prevBuf][3][lane];
            colpart[(size_t)I * NROWS + prevColBase + lane] = v;
        }
        if (t + 1 < nt) STAGE(cur ^ 1, jt + 16);   // async prefetch, zero VGPR cost
        const char* sb = &smem[cur][0] + lbase;
        bf16x8 bf[4][4];
#pragma unroll
        for (int ct = 0; ct < 4; ++ct)
#pragma unroll
            for (int kk = 0; kk < 4; ++kk)
                bf[ct][kk] = *(const bf16x8*)(sb + ct * 4096 + ((kk * 64) ^ m64));
        float csum[4] = {0.f, 0.f, 0.f, 0.f};
        bool offdiag = (colBase >= rowBase + 256);
        if (colBase == waveRow) {
            BATCH_BODY(true);
        } else {
            BATCH_BODY(false);
        }
        if (offdiag) {                       // col sums: reduce over lk groups
#pragma unroll
            for (int ct = 0; ct < 4; ++ct) {
                float v = csum[ct];
                v += __shfl_xor(v, 16);
                v += __shfl_xor(v, 32);
                if (lk == 0) colredL[cur][w][ct * 16 + lr] = v;
            }
        }
        __syncthreads();                     // orders smem reuse + colredL publish
        prevColBase = offdiag ? colBase : -1;
        prevBuf = cur;
        cur ^= 1;
    }
    if (prevColBase >= 0 && w == ((nt + 3) & 3)) { // flush last tile's col partials
        float v = colredL[prevBuf][0][lane] + colredL[prevBuf][1][lane] +
                  colredL[prevBuf][2][lane] + colredL[prevBuf][3][lane];
        colpart[(size_t)I * NROWS + prevColBase + lane] = v;
    }
#undef STAGE
#undef BATCH_BODY

    // reduce the 16 col-lanes of each row group, write deterministic row partials
#pragma unroll
    for (int r = 0; r < 4; ++r)
#pragma unroll
        for (int q = 0; q < 4; ++q) {
            float v = acc[r][q];
            v += __shfl_xor(v, 1);
            v += __shfl_xor(v, 2);
            v += __shfl_xor(v, 4);
            v += __shfl_xor(v, 8);
            if (lr == 0)
                rowpart[(size_t)s * NROWS + waveRow + r * 16 + lk * 4 + q] = v;
        }
}

// K3a: per-row loss terms + block partial sums. 64 blocks x 256 threads.
// neg[i] = sum_s rowpart[s][i] + sum_{I < i>>8} colpart[I][i]  (symmetric half)
__global__ __launch_bounds__(256) void k_loss1(const float* __restrict__ pos,
                                               const float* __restrict__ rowpart,
                                               const float* __restrict__ colpart,
                                               float* __restrict__ bsum) {
    int i = blockIdx.x * 256 + threadIdx.x;
    float neg = 0.f;
#pragma unroll
    for (int s = 0; s < NSPLIT; ++s) neg += rowpart[(size_t)s * NROWS + i];
    int M = i >> 8;                          // block-uniform
    for (int I = 0; I < M; ++I) neg += colpart[(size_t)I * NROWS + i];
    neg *= E_M2; // folded (sim - 2.0) shift
    float p = pos[i & (B_ROWS - 1)];
    float Ng = fmaxf((neg - 819.2f * p) * (1.0f / 0.9f), 8192.0f * E_M2);
    float l = fast_log2((p + Ng + 1e-8f) / p) * 0.69314718056f; // = -log(p/(p+Ng+eps))
#pragma unroll
    for (int m = 32; m; m >>= 1) l += __shfl_xor(l, m);
    __shared__ float s4[4];
    int wv = threadIdx.x >> 6;
    if ((threadIdx.x & 63) == 0) s4[wv] = l;
    __syncthreads();
    if (threadIdx.x == 0) bsum[blockIdx.x] = s4[0] + s4[1] + s4[2] + s4[3];
}

// K3b: final reduce of 64 block sums. 1 block, 1 wave.
__global__ void k_loss2(const float* __restrict__ bsum, float* __restrict__ out) {
    float v = bsum[threadIdx.x];
#pragma unroll
    for (int m = 32; m; m >>= 1) v += __shfl_xor(v, m);
    if (threadIdx.x == 0) out[0] = v * (1.0f / (float)NROWS);
}

extern "C" void kernel_launch(void* const* d_in, const int* in_sizes, int n_in,
                              void* d_out, int out_size, void* d_ws, size_t ws_size,
                              hipStream_t stream) {
    const float* zi = (const float*)d_in[0];
    const float* zj = (const float*)d_in[1];
    unsigned short* reps = (unsigned short*)d_ws;                    // 16384*128 bf16 = 4 MB
    float* pos = (float*)((char*)d_ws + (size_t)NROWS * D * 2);      // 8192 f32
    float* rowpart = pos + B_ROWS;                                   // 16*16384 f32 = 1 MB
    float* colpart = rowpart + (size_t)NSPLIT * NROWS;               // 64*16384 f32 = 4 MB
    float* bsum = colpart + (size_t)NCHUNK * NROWS;                  // 64 f32
    float* out = (float*)d_out;

    k_norm<<<B_ROWS / 4, 256, 0, stream>>>(zi, zj, (unsigned*)reps, pos);
    k_negsum<<<NCHUNK * NSPLIT, 256, 0, stream>>>(reps, rowpart, colpart);
    k_loss1<<<NROWS / 256, 256, 0, stream>>>(pos, rowpart, colpart, bsum);
    k_loss2<<<1, 64, 0, stream>>>(bsum, out);
}

// Round 9
// 78.931 us; speedup vs baseline: 1.0459x; 1.0459x over previous
//
#include <hip/hip_runtime.h>
#include <hip/hip_bf16.h>

typedef __attribute__((ext_vector_type(8))) short bf16x8;
typedef __attribute__((ext_vector_type(4))) float f32x4;

#define B_ROWS 8192
#define NROWS 16384             // 2B
#define D 128
#define C1 2.8853900817779268f  // 2*log2(e)  (sim = 2*cos; exp(x)=2^(x*log2e))
#define E_M2 0.13533528323661270f // exp(-2) == 2^(-C1): the folded row-max shift
#define RSCALE 1.6986436f       // sqrt(C1), folded into reps on both operands
#define TILE_COLS 64
#define TILE_BYTES (TILE_COLS * D * 2) // 16 KB per buffer
#define SMAX 32                 // max lists per row-chunk (I=0,1)
#define NBLK 1056               // sum_{I<64} (32 - (I>>1))
#define NSLICE 8

// Raw hardware exp2/log2: args are bounded, no range handling needed.
__device__ __forceinline__ float fast_exp2(float x) {
#if __has_builtin(__builtin_amdgcn_exp2f)
    return __builtin_amdgcn_exp2f(x);
#else
    float r; asm("v_exp_f32 %0, %1" : "=v"(r) : "v"(x)); return r;
#endif
}
__device__ __forceinline__ float fast_log2(float x) {
#if __has_builtin(__builtin_amdgcn_logf)
    return __builtin_amdgcn_logf(x);
#else
    float r; asm("v_log_f32 %0, %1" : "=v"(r) : "v"(x)); return r;
#endif
}

__device__ __forceinline__ unsigned short f2bf(float f) {
    union { float f; unsigned u; } v; v.f = f;
    unsigned r = v.u + 0x7FFFu + ((v.u >> 16) & 1u); // RNE
    return (unsigned short)(r >> 16);
}

// triangular colpart offset: slab I holds cols [256(I+1), NROWS)
__device__ __host__ __forceinline__ int colpart_off(int I) {
    return I * NROWS - 128 * I * (I + 1);
}

// K1: row norms + positive dots + bf16 reps (pre-scaled by sqrt(C1)).
__global__ __launch_bounds__(256) void k_norm(const float* __restrict__ zi,
                                              const float* __restrict__ zj,
                                              unsigned* __restrict__ repsU,
                                              float* __restrict__ pos) {
    int w = threadIdx.x >> 6, lane = threadIdx.x & 63;
    int row = blockIdx.x * 4 + w;
    const float2* a2 = (const float2*)(zi + (size_t)row * D);
    const float2* b2 = (const float2*)(zj + (size_t)row * D);
    float2 a = a2[lane], b = b2[lane];
    float si = a.x * a.x + a.y * a.y;
    float sj = b.x * b.x + b.y * b.y;
    float sd = a.x * b.x + a.y * b.y;
#pragma unroll
    for (int m = 32; m; m >>= 1) {
        si += __shfl_xor(si, m);
        sj += __shfl_xor(sj, m);
        sd += __shfl_xor(sd, m);
    }
    float inv_i = 1.0f / fmaxf(sqrtf(si), 1e-12f);
    float inv_j = 1.0f / fmaxf(sqrtf(sj), 1e-12f);
    float sa = inv_i * RSCALE, sb = inv_j * RSCALE;
    repsU[(size_t)row * 64 + lane] =
        (unsigned)f2bf(a.x * sa) | ((unsigned)f2bf(a.y * sa) << 16);
    repsU[(size_t)(row + B_ROWS) * 64 + lane] =
        (unsigned)f2bf(b.x * sb) | ((unsigned)f2bf(b.y * sb) << 16);
    if (lane == 0) pos[row] = fast_exp2(sd * inv_i * inv_j * C1); // exp(2*cos_ij)
}

// K2: symmetric-half fused sim-GEMM + exp + row/col sums — UNIFORM blocks.
// Row-chunk I (rows [256I,256I+256)) owns col-tiles j in [4I,256), split into
// S_I = 32-(I>>1) interleaved lists of 7-8 tiles each -> 1056 equal blocks
// (R8 lesson: variable-size blocks + in-order dispatch cluster heavy blocks
// on the same CUs; makespan = heavy cluster, not average).
// Off-diag tiles also emit column sums (= transposed rows) via csum ->
// lk-shuffle -> colredL -> one wave stores to triangular colpart.
// C/D layout (m89-verified): row=(lane>>4)*4+q, col=lane&15.
__global__ __launch_bounds__(256, 2) void k_negsum(const unsigned short* __restrict__ R,
                                                   float* __restrict__ rowpart,
                                                   float* __restrict__ colpart) {
    __shared__ char smem[2][TILE_BYTES];
    __shared__ float colredL[2][4][64];
    // block -> (I, s): S_I = 32 - (I>>1)
    int b = blockIdx.x, I = 0;
    for (;;) { int S = 32 - (I >> 1); if (b < S) break; b -= S; ++I; }
    int s = b;
    int S_I = 32 - (I >> 1);
    int rowBase = I << 8;
    int jstart = (I << 2) + s;              // first col-tile
    int L_I = 256 - (I << 2);
    int nt = (L_I - s + S_I - 1) / S_I;     // 7 or 8

    int w = threadIdx.x >> 6;
    int lane = threadIdx.x & 63;
    int lr = lane & 15, lk = lane >> 4;
    int waveRow = rowBase + w * 64;

    bf16x8 afrag[4][4];
#pragma unroll
    for (int r = 0; r < 4; ++r)
#pragma unroll
        for (int kk = 0; kk < 4; ++kk)
            afrag[r][kk] = *(const bf16x8*)(R + (size_t)(waveRow + r * 16 + lr) * D + kk * 32 + lk * 8);

    // staging: instruction j of wave w covers dest bytes (w*4+j)*1024 + lane*16
    int srcoff[4], dstoff[4];
#pragma unroll
    for (int j = 0; j < 4; ++j) {
        int o = (w * 4 + j) * 1024 + lane * 16;
        int row = o >> 8, c = o & 255;
        srcoff[j] = row * 256 + (c ^ ((row & 7) << 4)); // pre-swizzled global source
        dstoff[j] = (w * 4 + j) * 1024;                 // wave-uniform LDS base
    }

    const char* Rb = (const char*)R;

    // swizzled read-offset components: lds_off(ct,kk) = ct*4096 + lbase + (kk*64 ^ m64)
    int m64 = (lr & 4) << 4;
    int lbase = lr * 256 + ((lk * 16) ^ ((lr & 3) << 4));

    float acc[4][4] = {};

#define STAGE(buf, jj)                                                            \
    do {                                                                          \
        const char* tb_ = Rb + (size_t)(jj) * (TILE_COLS * 256);                  \
        _Pragma("unroll")                                                         \
        for (int j = 0; j < 4; ++j)                                               \
            __builtin_amdgcn_global_load_lds(                                     \
                (const __attribute__((address_space(1))) unsigned*)(tb_ + srcoff[j]), \
                (__attribute__((address_space(3))) unsigned*)(&smem[buf][dstoff[j]]), \
                16, 0, 0);                                                        \
    } while (0)

#define BATCH_BODY(DIAG)                                                          \
    do {                                                                          \
        _Pragma("unroll")                                                         \
        for (int ct = 0; ct < 4; ++ct) {                                          \
            _Pragma("unroll")                                                     \
            for (int r = 0; r < 4; ++r) {                                         \
                f32x4 c = {0.f, 0.f, 0.f, 0.f};                                   \
                c = __builtin_amdgcn_mfma_f32_16x16x32_bf16(afrag[r][0], bf[ct][0], c, 0, 0, 0); \
                c = __builtin_amdgcn_mfma_f32_16x16x32_bf16(afrag[r][1], bf[ct][1], c, 0, 0, 0); \
                c = __builtin_amdgcn_mfma_f32_16x16x32_bf16(afrag[r][2], bf[ct][2], c, 0, 0, 0); \
                c = __builtin_amdgcn_mfma_f32_16x16x32_bf16(afrag[r][3], bf[ct][3], c, 0, 0, 0); \
                if (DIAG && ct == r) {                                            \
                    _Pragma("unroll")                                             \
                    for (int q = 0; q < 4; ++q)                                   \
                        if (lk * 4 + q != lr) {                                   \
                            float e = fast_exp2(c[q]);                            \
                            acc[r][q] += e; csum[ct] += e;                        \
                        }                                                         \
                } else {                                                          \
                    _Pragma("unroll")                                             \
                    for (int q = 0; q < 4; ++q) {                                 \
                        float e = fast_exp2(c[q]);                                \
                        acc[r][q] += e; csum[ct] += e;                            \
                    }                                                             \
                }                                                                 \
            }                                                                     \
        }                                                                         \
    } while (0)

    STAGE(0, jstart);
    __syncthreads();                         // drains vmcnt(0) before first reads
    int cur = 0;
    int prevColBase = -1, prevBuf = 0;
    for (int t = 0; t < nt; ++t) {
        int jt = jstart + t * S_I;
        int colBase = jt << 6;
        // store previous off-diag tile's column partials (one rotating wave)
        if (prevColBase >= 0 && w == ((t + 3) & 3)) {
            float v = colredL[prevBuf][0][lane] + colredL[prevBuf][1][lane] +
                      colredL[prevBuf][2][lane] + colredL[prevBuf][3][lane];
            colpart[colpart_off(I) + prevColBase + lane - ((I + 1) << 8)] = v;
        }
        if (t + 1 < nt) STAGE(cur ^ 1, jt + S_I);   // async prefetch, zero VGPR cost
        const char* sb = &smem[cur][0] + lbase;
        bf16x8 bf[4][4];
#pragma unroll
        for (int ct = 0; ct < 4; ++ct)
#pragma unroll
            for (int kk = 0; kk < 4; ++kk)
                bf[ct][kk] = *(const bf16x8*)(sb + ct * 4096 + ((kk * 64) ^ m64));
        float csum[4] = {0.f, 0.f, 0.f, 0.f};
        bool offdiag = (colBase >= rowBase + 256);
        if (colBase == waveRow) {
            BATCH_BODY(true);
        } else {
            BATCH_BODY(false);
        }
        if (offdiag) {                       // col sums: reduce over lk groups
#pragma unroll
            for (int ct = 0; ct < 4; ++ct) {
                float v = csum[ct];
                v += __shfl_xor(v, 16);
                v += __shfl_xor(v, 32);
                if (lk == 0) colredL[cur][w][ct * 16 + lr] = v;
            }
        }
        __syncthreads();                     // orders smem reuse + colredL publish
        prevColBase = offdiag ? colBase : -1;
        prevBuf = cur;
        cur ^= 1;
    }
    if (prevColBase >= 0 && w == ((nt + 3) & 3)) { // flush last tile's col partials
        float v = colredL[prevBuf][0][lane] + colredL[prevBuf][1][lane] +
                  colredL[prevBuf][2][lane] + colredL[prevBuf][3][lane];
        colpart[colpart_off(I) + prevColBase + lane - ((I + 1) << 8)] = v;
    }
#undef STAGE
#undef BATCH_BODY

    // reduce the 16 col-lanes of each row group, write deterministic row partials
#pragma unroll
    for (int r = 0; r < 4; ++r)
#pragma unroll
        for (int q = 0; q < 4; ++q) {
            float v = acc[r][q];
            v += __shfl_xor(v, 1);
            v += __shfl_xor(v, 2);
            v += __shfl_xor(v, 4);
            v += __shfl_xor(v, 8);
            if (lr == 0)
                rowpart[(size_t)s * NROWS + waveRow + r * 16 + lk * 4 + q] = v;
        }
}

// K2b: slice-parallel partial reduction of rowpart+colpart -> negp[8][N].
// 512 blocks; <=12 independent coalesced loads per thread (R8 lesson: the
// 63-deep block-uniform slab loop at 64 blocks was a naked latency chain).
__global__ __launch_bounds__(256) void k_negred(const float* __restrict__ rowpart,
                                                const float* __restrict__ colpart,
                                                float* __restrict__ negp) {
    int g = blockIdx.x >> 3;                // row group: rows [256g, 256g+256)
    int z = blockIdx.x & (NSLICE - 1);
    int i = g * 256 + threadIdx.x;
    int S_I = 32 - (g >> 1);
    float a = 0.f;
    for (int s = z; s < S_I; s += NSLICE)   // <=4 iterations
        a += rowpart[(size_t)s * NROWS + i];
    for (int I = z; I < g; I += NSLICE)     // <=8 iterations
        a += colpart[colpart_off(I) + i - ((I + 1) << 8)];
    negp[(size_t)z * NROWS + i] = a;
}

// K3a: per-row loss terms + block partial sums. 64 blocks x 256 threads.
__global__ __launch_bounds__(256) void k_loss1(const float* __restrict__ pos,
                                               const float* __restrict__ negp,
                                               float* __restrict__ bsum) {
    int i = blockIdx.x * 256 + threadIdx.x;
    float neg = 0.f;
#pragma unroll
    for (int z = 0; z < NSLICE; ++z) neg += negp[(size_t)z * NROWS + i];
    neg *= E_M2; // folded (sim - 2.0) shift
    float p = pos[i & (B_ROWS - 1)];
    float Ng = fmaxf((neg - 819.2f * p) * (1.0f / 0.9f), 8192.0f * E_M2);
    float l = fast_log2((p + Ng + 1e-8f) / p) * 0.69314718056f; // = -log(p/(p+Ng+eps))
#pragma unroll
    for (int m = 32; m; m >>= 1) l += __shfl_xor(l, m);
    __shared__ float s4[4];
    int wv = threadIdx.x >> 6;
    if ((threadIdx.x & 63) == 0) s4[wv] = l;
    __syncthreads();
    if (threadIdx.x == 0) bsum[blockIdx.x] = s4[0] + s4[1] + s4[2] + s4[3];
}

// K3b: final reduce of 64 block sums. 1 block, 1 wave.
__global__ void k_loss2(const float* __restrict__ bsum, float* __restrict__ out) {
    float v = bsum[threadIdx.x];
#pragma unroll
    for (int m = 32; m; m >>= 1) v += __shfl_xor(v, m);
    if (threadIdx.x == 0) out[0] = v * (1.0f / (float)NROWS);
}

extern "C" void kernel_launch(void* const* d_in, const int* in_sizes, int n_in,
                              void* d_out, int out_size, void* d_ws, size_t ws_size,
                              hipStream_t stream) {
    const float* zi = (const float*)d_in[0];
    const float* zj = (const float*)d_in[1];
    char* ws = (char*)d_ws;
    unsigned short* reps = (unsigned short*)ws;            // 4 MB
    float* pos = (float*)(ws + 4194304);                   // 32 KB
    float* rowpart = pos + B_ROWS;                         // 32*16384*4 = 2 MB
    float* colpart = rowpart + (size_t)SMAX * NROWS;       // 516096*4 ~= 2 MB (triangular)
    float* negp = colpart + 516096;                        // 8*16384*4 = 512 KB
    float* bsum = negp + (size_t)NSLICE * NROWS;           // 256 B
    float* out = (float*)d_out;                            // total ~8.9 MB

    k_norm<<<B_ROWS / 4, 256, 0, stream>>>(zi, zj, (unsigned*)reps, pos);
    k_negsum<<<NBLK, 256, 0, stream>>>(reps, rowpart, colpart);
    k_negred<<<64 * NSLICE, 256, 0, stream>>>(rowpart, colpart, negp);
    k_loss1<<<NROWS / 256, 256, 0, stream>>>(pos, negp, bsum);
    k_loss2<<<1, 64, 0, stream>>>(bsum, out);
}

// Round 10
// 65.929 us; speedup vs baseline: 1.2522x; 1.1972x over previous
//
#include <hip/hip_runtime.h>
#include <hip/hip_bf16.h>

typedef __attribute__((ext_vector_type(8))) short bf16x8;
typedef __attribute__((ext_vector_type(4))) float f32x4;

#define B_ROWS 8192
#define NROWS 16384             // 2B
#define D 128
#define C1 2.8853900817779268f  // 2*log2(e)  (sim = 2*cos; exp(x)=2^(x*log2e))
#define E_M2 0.13533528323661270f // exp(-2) == 2^(-C1): the folded row-max shift
#define RSCALE 1.6986436f       // sqrt(C1), folded into reps on both operands
#define TILE_COLS 64
#define TILE_BYTES (TILE_COLS * D * 2) // 16 KB per buffer
#define NSPLIT 16               // lists per row-chunk (R8 scheme; R9 uniformizing regressed)
#define NBLK (64 * NSPLIT)      // 1024
#define NSLICE 8

// Raw hardware exp2/log2: args are bounded, no range handling needed.
__device__ __forceinline__ float fast_exp2(float x) {
#if __has_builtin(__builtin_amdgcn_exp2f)
    return __builtin_amdgcn_exp2f(x);
#else
    float r; asm("v_exp_f32 %0, %1" : "=v"(r) : "v"(x)); return r;
#endif
}
__device__ __forceinline__ float fast_log2(float x) {
#if __has_builtin(__builtin_amdgcn_logf)
    return __builtin_amdgcn_logf(x);
#else
    float r; asm("v_log_f32 %0, %1" : "=v"(r) : "v"(x)); return r;
#endif
}

__device__ __forceinline__ unsigned short f2bf(float f) {
    union { float f; unsigned u; } v; v.f = f;
    unsigned r = v.u + 0x7FFFu + ((v.u >> 16) & 1u); // RNE
    return (unsigned short)(r >> 16);
}

// triangular colpart offset: slab I holds cols [256(I+1), NROWS)
__device__ __host__ __forceinline__ int colpart_off(int I) {
    return I * NROWS - 128 * I * (I + 1);
}

// K1: row norms + positive dots + bf16 reps (pre-scaled by sqrt(C1)).
__global__ __launch_bounds__(256) void k_norm(const float* __restrict__ zi,
                                              const float* __restrict__ zj,
                                              unsigned* __restrict__ repsU,
                                              float* __restrict__ pos) {
    int w = threadIdx.x >> 6, lane = threadIdx.x & 63;
    int row = blockIdx.x * 4 + w;
    const float2* a2 = (const float2*)(zi + (size_t)row * D);
    const float2* b2 = (const float2*)(zj + (size_t)row * D);
    float2 a = a2[lane], b = b2[lane];
    float si = a.x * a.x + a.y * a.y;
    float sj = b.x * b.x + b.y * b.y;
    float sd = a.x * b.x + a.y * b.y;
#pragma unroll
    for (int m = 32; m; m >>= 1) {
        si += __shfl_xor(si, m);
        sj += __shfl_xor(sj, m);
        sd += __shfl_xor(sd, m);
    }
    float inv_i = 1.0f / fmaxf(sqrtf(si), 1e-12f);
    float inv_j = 1.0f / fmaxf(sqrtf(sj), 1e-12f);
    float sa = inv_i * RSCALE, sb = inv_j * RSCALE;
    repsU[(size_t)row * 64 + lane] =
        (unsigned)f2bf(a.x * sa) | ((unsigned)f2bf(a.y * sa) << 16);
    repsU[(size_t)(row + B_ROWS) * 64 + lane] =
        (unsigned)f2bf(b.x * sb) | ((unsigned)f2bf(b.y * sb) << 16);
    if (lane == 0) pos[row] = fast_exp2(sd * inv_i * inv_j * C1); // exp(2*cos_ij)
}

// K2: symmetric-half fused sim-GEMM + exp + row/col sums (R8 decomposition,
// shuffle-free column path). Row-chunk I owns col-tiles j in [4I,256); list s
// takes j = 4I+dph, stride 16 (nt = 4..16; I-major dispatch, R9 lesson:
// uniformizing regressed; R8's in-order I-major already hit avg makespan).
// Column sums: per-lane csum -> 4 plain ds_write into colacc[par][w][lk][80]
// (pad-80 -> 2-way banks = free); one rotating wave flushes the PREVIOUS
// tile's slots (16 conflict-free ds_read + 1 store). No shuffles in the loop
// (R9 lesson: 8 shfl_xor/wave-tile = ds_bpermute ~960 cyc/tile on the shared
// LDS pipe was the +55% per-tile inflation).
// C/D layout (m89-verified): row=(lane>>4)*4+q, col=lane&15.
__global__ __launch_bounds__(256, 2) void k_negsum(const unsigned short* __restrict__ R,
                                                   float* __restrict__ rowpart,
                                                   float* __restrict__ colpart) {
    __shared__ char smem[2][TILE_BYTES];
    __shared__ float colacc[2][4][4][80];   // [parity][w][lk][col+pad]
    int I = blockIdx.x >> 4;
    int s = blockIdx.x & (NSPLIT - 1);
    int rowBase = I << 8;
    int dph = (s - ((I << 2) & 15)) & 15;
    int jstart = (I << 2) + dph;            // first col-tile of this list
    int nt = (jstart < 256) ? (((255 - jstart) >> 4) + 1) : 0;

    int w = threadIdx.x >> 6;
    int lane = threadIdx.x & 63;
    int lr = lane & 15, lk = lane >> 4;
    int waveRow = rowBase + w * 64;

    bf16x8 afrag[4][4];
#pragma unroll
    for (int r = 0; r < 4; ++r)
#pragma unroll
        for (int kk = 0; kk < 4; ++kk)
            afrag[r][kk] = *(const bf16x8*)(R + (size_t)(waveRow + r * 16 + lr) * D + kk * 32 + lk * 8);

    // staging: instruction j of wave w covers dest bytes (w*4+j)*1024 + lane*16
    int srcoff[4], dstoff[4];
#pragma unroll
    for (int j = 0; j < 4; ++j) {
        int o = (w * 4 + j) * 1024 + lane * 16;
        int row = o >> 8, c = o & 255;
        srcoff[j] = row * 256 + (c ^ ((row & 7) << 4)); // pre-swizzled global source
        dstoff[j] = (w * 4 + j) * 1024;                 // wave-uniform LDS base
    }

    const char* Rb = (const char*)R;

    // swizzled read-offset components: lds_off(ct,kk) = ct*4096 + lbase + (kk*64 ^ m64)
    int m64 = (lr & 4) << 4;
    int lbase = lr * 256 + ((lk * 16) ^ ((lr & 3) << 4));

    float acc[4][4] = {};

#define STAGE(buf, jj)                                                            \
    do {                                                                          \
        const char* tb_ = Rb + (size_t)(jj) * (TILE_COLS * 256);                  \
        _Pragma("unroll")                                                         \
        for (int j = 0; j < 4; ++j)                                               \
            __builtin_amdgcn_global_load_lds(                                     \
                (const __attribute__((address_space(1))) unsigned*)(tb_ + srcoff[j]), \
                (__attribute__((address_space(3))) unsigned*)(&smem[buf][dstoff[j]]), \
                16, 0, 0);                                                        \
    } while (0)

#define BATCH_BODY(DIAG)                                                          \
    do {                                                                          \
        _Pragma("unroll")                                                         \
        for (int ct = 0; ct < 4; ++ct) {                                          \
            _Pragma("unroll")                                                     \
            for (int r = 0; r < 4; ++r) {                                         \
                f32x4 c = {0.f, 0.f, 0.f, 0.f};                                   \
                c = __builtin_amdgcn_mfma_f32_16x16x32_bf16(afrag[r][0], bf[ct][0], c, 0, 0, 0); \
                c = __builtin_amdgcn_mfma_f32_16x16x32_bf16(afrag[r][1], bf[ct][1], c, 0, 0, 0); \
                c = __builtin_amdgcn_mfma_f32_16x16x32_bf16(afrag[r][2], bf[ct][2], c, 0, 0, 0); \
                c = __builtin_amdgcn_mfma_f32_16x16x32_bf16(afrag[r][3], bf[ct][3], c, 0, 0, 0); \
                if (DIAG && ct == r) {                                            \
                    _Pragma("unroll")                                             \
                    for (int q = 0; q < 4; ++q)                                   \
                        if (lk * 4 + q != lr) {                                   \
                            float e = fast_exp2(c[q]);                            \
                            acc[r][q] += e; csum[ct] += e;                        \
                        }                                                         \
                } else {                                                          \
                    _Pragma("unroll")                                             \
                    for (int q = 0; q < 4; ++q) {                                 \
                        float e = fast_exp2(c[q]);                                \
                        acc[r][q] += e; csum[ct] += e;                            \
                    }                                                             \
                }                                                                 \
            }                                                                     \
        }                                                                         \
    } while (0)

    if (nt > 0) STAGE(0, jstart);
    __syncthreads();                         // drains vmcnt(0) before first reads
    int cur = 0;
    for (int t = 0; t < nt; ++t) {
        int jt = jstart + (t << 4);
        int colBase = jt << 6;
        // flush PREVIOUS tile's column partials (one rotating wave; parity
        // (t-1)&1 != t&1, so no race with this tile's colacc writes)
        if (t > 0 && w == ((t + 3) & 3)) {
            int pcb = colBase - 1024;        // (jt-16)<<6
            if (pcb >= rowBase + 256) {
                int par = (t - 1) & 1;
                float v = 0.f;
#pragma unroll
                for (int u = 0; u < 16; ++u) v += colacc[par][u >> 2][u & 3][lane];
                colpart[colpart_off(I) + pcb + lane - ((I + 1) << 8)] = v;
            }
        }
        if (t + 1 < nt) STAGE(cur ^ 1, jt + 16);   // async prefetch, zero VGPR cost
        const char* sb = &smem[cur][0] + lbase;
        bf16x8 bf[4][4];
#pragma unroll
        for (int ct = 0; ct < 4; ++ct)
#pragma unroll
            for (int kk = 0; kk < 4; ++kk)
                bf[ct][kk] = *(const bf16x8*)(sb + ct * 4096 + ((kk * 64) ^ m64));
        float csum[4] = {0.f, 0.f, 0.f, 0.f};
        bool offdiag = (colBase >= rowBase + 256);
        if (colBase == waveRow) {
            BATCH_BODY(true);
        } else {
            BATCH_BODY(false);
        }
        if (offdiag) {                       // per-lane-owned slots, no shuffles
            int par = t & 1;
#pragma unroll
            for (int ct = 0; ct < 4; ++ct)
                colacc[par][w][lk][ct * 16 + lr] = csum[ct];
        }
        __syncthreads();                     // orders smem dbuf + colacc publish
        cur ^= 1;
    }
    if (nt > 0 && w == ((nt + 3) & 3)) {     // flush last tile's column partials
        int pcb = (jstart + ((nt - 1) << 4)) << 6;
        if (pcb >= rowBase + 256) {
            int par = (nt - 1) & 1;
            float v = 0.f;
#pragma unroll
            for (int u = 0; u < 16; ++u) v += colacc[par][u >> 2][u & 3][lane];
            colpart[colpart_off(I) + pcb + lane - ((I + 1) << 8)] = v;
        }
    }
#undef STAGE
#undef BATCH_BODY

    // reduce the 16 col-lanes of each row group, write deterministic row partials
    // (empty lists still write zeros so k_negred can sum all 16 slabs)
#pragma unroll
    for (int r = 0; r < 4; ++r)
#pragma unroll
        for (int q = 0; q < 4; ++q) {
            float v = acc[r][q];
            v += __shfl_xor(v, 1);
            v += __shfl_xor(v, 2);
            v += __shfl_xor(v, 4);
            v += __shfl_xor(v, 8);
            if (lr == 0)
                rowpart[(size_t)s * NROWS + waveRow + r * 16 + lk * 4 + q] = v;
        }
}

// K2b: slice-parallel partial reduction of rowpart+colpart -> negp[8][N].
// 512 blocks; <=10 independent coalesced loads per thread.
__global__ __launch_bounds__(256) void k_negred(const float* __restrict__ rowpart,
                                                const float* __restrict__ colpart,
                                                float* __restrict__ negp) {
    int g = blockIdx.x >> 3;                // row group: rows [256g, 256g+256)
    int z = blockIdx.x & (NSLICE - 1);
    int i = g * 256 + threadIdx.x;
    float a = 0.f;
#pragma unroll
    for (int s = z; s < NSPLIT; s += NSLICE) // 2 iterations
        a += rowpart[(size_t)s * NROWS + i];
    for (int I = z; I < g; I += NSLICE)      // <=8 iterations
        a += colpart[colpart_off(I) + i - ((I + 1) << 8)];
    negp[(size_t)z * NROWS + i] = a;
}

// K3a: per-row loss terms + block partial sums. 64 blocks x 256 threads.
__global__ __launch_bounds__(256) void k_loss1(const float* __restrict__ pos,
                                               const float* __restrict__ negp,
                                               float* __restrict__ bsum) {
    int i = blockIdx.x * 256 + threadIdx.x;
    float neg = 0.f;
#pragma unroll
    for (int z = 0; z < NSLICE; ++z) neg += negp[(size_t)z * NROWS + i];
    neg *= E_M2; // folded (sim - 2.0) shift
    float p = pos[i & (B_ROWS - 1)];
    float Ng = fmaxf((neg - 819.2f * p) * (1.0f / 0.9f), 8192.0f * E_M2);
    float l = fast_log2((p + Ng + 1e-8f) / p) * 0.69314718056f; // = -log(p/(p+Ng+eps))
#pragma unroll
    for (int m = 32; m; m >>= 1) l += __shfl_xor(l, m);
    __shared__ float s4[4];
    int wv = threadIdx.x >> 6;
    if ((threadIdx.x & 63) == 0) s4[wv] = l;
    __syncthreads();
    if (threadIdx.x == 0) bsum[blockIdx.x] = s4[0] + s4[1] + s4[2] + s4[3];
}

// K3b: final reduce of 64 block sums. 1 block, 1 wave.
__global__ void k_loss2(const float* __restrict__ bsum, float* __restrict__ out) {
    float v = bsum[threadIdx.x];
#pragma unroll
    for (int m = 32; m; m >>= 1) v += __shfl_xor(v, m);
    if (threadIdx.x == 0) out[0] = v * (1.0f / (float)NROWS);
}

extern "C" void kernel_launch(void* const* d_in, const int* in_sizes, int n_in,
                              void* d_out, int out_size, void* d_ws, size_t ws_size,
                              hipStream_t stream) {
    const float* zi = (const float*)d_in[0];
    const float* zj = (const float*)d_in[1];
    char* ws = (char*)d_ws;
    unsigned short* reps = (unsigned short*)ws;            // 4 MB
    float* pos = (float*)(ws + 4194304);                   // 32 KB
    float* rowpart = pos + B_ROWS;                         // 16*16384*4 = 1 MB
    float* colpart = rowpart + (size_t)NSPLIT * NROWS;     // 516096*4 ~= 2 MB (triangular)
    float* negp = colpart + 516096;                        // 8*16384*4 = 512 KB
    float* bsum = negp + (size_t)NSLICE * NROWS;           // 256 B
    float* out = (float*)d_out;                            // total ~7.6 MB

    k_norm<<<B_ROWS / 4, 256, 0, stream>>>(zi, zj, (unsigned*)reps, pos);
    k_negsum<<<NBLK, 256, 0, stream>>>(reps, rowpart, colpart);
    k_negred<<<64 * NSLICE, 256, 0, stream>>>(rowpart, colpart, negp);
    k_loss1<<<NROWS / 256, 256, 0, stream>>>(pos, negp, bsum);
    k_loss2<<<1, 64, 0, stream>>>(bsum, out);
}

// Round 11
// 65.454 us; speedup vs baseline: 1.2613x; 1.0073x over previous
//
#include <hip/hip_runtime.h>
#include <hip/hip_bf16.h>

typedef __attribute__((ext_vector_type(8))) short bf16x8;
typedef __attribute__((ext_vector_type(4))) float f32x4;

#define B_ROWS 8192
#define NROWS 16384             // 2B
#define D 128
#define C1 2.8853900817779268f  // 2*log2(e)  (sim = 2*cos; exp(x)=2^(x*log2e))
#define E_M2 0.13533528323661270f // exp(-2) == 2^(-C1): the folded row-max shift
#define RSCALE 1.6986436f       // sqrt(C1), folded into reps on both operands
#define TILE_COLS 64
#define TILE_BYTES (TILE_COLS * D * 2) // 16 KB per buffer
#define NSPLIT 16               // lists per row-chunk (R8 scheme)
#define NBLK (64 * NSPLIT)      // 1024
#define NSLICE 8

// Raw hardware exp2/log2: args are bounded, no range handling needed.
__device__ __forceinline__ float fast_exp2(float x) {
#if __has_builtin(__builtin_amdgcn_exp2f)
    return __builtin_amdgcn_exp2f(x);
#else
    float r; asm("v_exp_f32 %0, %1" : "=v"(r) : "v"(x)); return r;
#endif
}
__device__ __forceinline__ float fast_log2(float x) {
#if __has_builtin(__builtin_amdgcn_logf)
    return __builtin_amdgcn_logf(x);
#else
    float r; asm("v_log_f32 %0, %1" : "=v"(r) : "v"(x)); return r;
#endif
}

__device__ __forceinline__ unsigned short f2bf(float f) {
    union { float f; unsigned u; } v; v.f = f;
    unsigned r = v.u + 0x7FFFu + ((v.u >> 16) & 1u); // RNE
    return (unsigned short)(r >> 16);
}

// triangular colpart offset: slab I holds cols [256(I+1), NROWS)
__device__ __host__ __forceinline__ int colpart_off(int I) {
    return I * NROWS - 128 * I * (I + 1);
}

// K1: row norms + positive dots + bf16 reps (pre-scaled by sqrt(C1)).
__global__ __launch_bounds__(256) void k_norm(const float* __restrict__ zi,
                                              const float* __restrict__ zj,
                                              unsigned* __restrict__ repsU,
                                              float* __restrict__ pos) {
    int w = threadIdx.x >> 6, lane = threadIdx.x & 63;
    int row = blockIdx.x * 4 + w;
    const float2* a2 = (const float2*)(zi + (size_t)row * D);
    const float2* b2 = (const float2*)(zj + (size_t)row * D);
    float2 a = a2[lane], b = b2[lane];
    float si = a.x * a.x + a.y * a.y;
    float sj = b.x * b.x + b.y * b.y;
    float sd = a.x * b.x + a.y * b.y;
#pragma unroll
    for (int m = 32; m; m >>= 1) {
        si += __shfl_xor(si, m);
        sj += __shfl_xor(sj, m);
        sd += __shfl_xor(sd, m);
    }
    float inv_i = 1.0f / fmaxf(sqrtf(si), 1e-12f);
    float inv_j = 1.0f / fmaxf(sqrtf(sj), 1e-12f);
    float sa = inv_i * RSCALE, sb = inv_j * RSCALE;
    repsU[(size_t)row * 64 + lane] =
        (unsigned)f2bf(a.x * sa) | ((unsigned)f2bf(a.y * sa) << 16);
    repsU[(size_t)(row + B_ROWS) * 64 + lane] =
        (unsigned)f2bf(b.x * sb) | ((unsigned)f2bf(b.y * sb) << 16);
    if (lane == 0) pos[row] = fast_exp2(sd * inv_i * inv_j * C1); // exp(2*cos_ij)
}

// K2: symmetric-half fused sim-GEMM + exp + row/col sums (R10 structure).
// R11 change: colacc relaid as [2][16][16][4] (8 KB, was 10 KB padded) so
// each lane stores its 4 csum values with ONE ds_write_b128 (linear lane*16B,
// conflict-free); flush reads colacc[par][u][c&15][c>>4] (2-way banks, free).
// Total LDS = 32768+8192 = 40960 = 160K/4 exactly -> 4 blocks/CU resident
// (was 3 at 43008): co-resident blocks fill each other's barrier drains.
// C/D layout (m89-verified): row=(lane>>4)*4+q, col=lane&15.
__global__ __launch_bounds__(256, 2) void k_negsum(const unsigned short* __restrict__ R,
                                                   float* __restrict__ rowpart,
                                                   float* __restrict__ colpart) {
    __shared__ char smem[2][TILE_BYTES];
    __shared__ float colacc[2][16][16][4];  // [parity][w*4+lk][lr][ct]
    int I = blockIdx.x >> 4;
    int s = blockIdx.x & (NSPLIT - 1);
    int rowBase = I << 8;
    int dph = (s - ((I << 2) & 15)) & 15;
    int jstart = (I << 2) + dph;            // first col-tile of this list
    int nt = (jstart < 256) ? (((255 - jstart) >> 4) + 1) : 0;

    int w = threadIdx.x >> 6;
    int lane = threadIdx.x & 63;
    int lr = lane & 15, lk = lane >> 4;
    int waveRow = rowBase + w * 64;

    bf16x8 afrag[4][4];
#pragma unroll
    for (int r = 0; r < 4; ++r)
#pragma unroll
        for (int kk = 0; kk < 4; ++kk)
            afrag[r][kk] = *(const bf16x8*)(R + (size_t)(waveRow + r * 16 + lr) * D + kk * 32 + lk * 8);

    // staging: instruction j of wave w covers dest bytes (w*4+j)*1024 + lane*16
    int srcoff[4], dstoff[4];
#pragma unroll
    for (int j = 0; j < 4; ++j) {
        int o = (w * 4 + j) * 1024 + lane * 16;
        int row = o >> 8, c = o & 255;
        srcoff[j] = row * 256 + (c ^ ((row & 7) << 4)); // pre-swizzled global source
        dstoff[j] = (w * 4 + j) * 1024;                 // wave-uniform LDS base
    }

    const char* Rb = (const char*)R;

    // swizzled read-offset components: lds_off(ct,kk) = ct*4096 + lbase + (kk*64 ^ m64)
    int m64 = (lr & 4) << 4;
    int lbase = lr * 256 + ((lk * 16) ^ ((lr & 3) << 4));

    float acc[4][4] = {};

#define STAGE(buf, jj)                                                            \
    do {                                                                          \
        const char* tb_ = Rb + (size_t)(jj) * (TILE_COLS * 256);                  \
        _Pragma("unroll")                                                         \
        for (int j = 0; j < 4; ++j)                                               \
            __builtin_amdgcn_global_load_lds(                                     \
                (const __attribute__((address_space(1))) unsigned*)(tb_ + srcoff[j]), \
                (__attribute__((address_space(3))) unsigned*)(&smem[buf][dstoff[j]]), \
                16, 0, 0);                                                        \
    } while (0)

#define BATCH_BODY(DIAG)                                                          \
    do {                                                                          \
        _Pragma("unroll")                                                         \
        for (int ct = 0; ct < 4; ++ct) {                                          \
            _Pragma("unroll")                                                     \
            for (int r = 0; r < 4; ++r) {                                         \
                f32x4 c = {0.f, 0.f, 0.f, 0.f};                                   \
                c = __builtin_amdgcn_mfma_f32_16x16x32_bf16(afrag[r][0], bf[ct][0], c, 0, 0, 0); \
                c = __builtin_amdgcn_mfma_f32_16x16x32_bf16(afrag[r][1], bf[ct][1], c, 0, 0, 0); \
                c = __builtin_amdgcn_mfma_f32_16x16x32_bf16(afrag[r][2], bf[ct][2], c, 0, 0, 0); \
                c = __builtin_amdgcn_mfma_f32_16x16x32_bf16(afrag[r][3], bf[ct][3], c, 0, 0, 0); \
                if (DIAG && ct == r) {                                            \
                    _Pragma("unroll")                                             \
                    for (int q = 0; q < 4; ++q)                                   \
                        if (lk * 4 + q != lr) {                                   \
                            float e = fast_exp2(c[q]);                            \
                            acc[r][q] += e; csum[ct] += e;                        \
                        }                                                         \
                } else {                                                          \
                    _Pragma("unroll")                                             \
                    for (int q = 0; q < 4; ++q) {                                 \
                        float e = fast_exp2(c[q]);                                \
                        acc[r][q] += e; csum[ct] += e;                            \
                    }                                                             \
                }                                                                 \
            }                                                                     \
        }                                                                         \
    } while (0)

    if (nt > 0) STAGE(0, jstart);
    __syncthreads();                         // drains vmcnt(0) before first reads
    int cur = 0;
    for (int t = 0; t < nt; ++t) {
        int jt = jstart + (t << 4);
        int colBase = jt << 6;
        // flush PREVIOUS tile's column partials (one rotating wave; parity
        // (t-1)&1 != t&1, so no race with this tile's colacc writes)
        if (t > 0 && w == ((t + 3) & 3)) {
            int pcb = colBase - 1024;        // (jt-16)<<6
            if (pcb >= rowBase + 256) {
                int par = (t - 1) & 1;
                float v = 0.f;
#pragma unroll
                for (int u = 0; u < 16; ++u) v += colacc[par][u][lane & 15][lane >> 4];
                colpart[colpart_off(I) + pcb + lane - ((I + 1) << 8)] = v;
            }
        }
        if (t + 1 < nt) STAGE(cur ^ 1, jt + 16);   // async prefetch, zero VGPR cost
        const char* sb = &smem[cur][0] + lbase;
        bf16x8 bf[4][4];
#pragma unroll
        for (int ct = 0; ct < 4; ++ct)
#pragma unroll
            for (int kk = 0; kk < 4; ++kk)
                bf[ct][kk] = *(const bf16x8*)(sb + ct * 4096 + ((kk * 64) ^ m64));
        float csum[4] = {0.f, 0.f, 0.f, 0.f};
        bool offdiag = (colBase >= rowBase + 256);
        if (colBase == waveRow) {
            BATCH_BODY(true);
        } else {
            BATCH_BODY(false);
        }
        if (offdiag) {                       // one b128 per lane, conflict-free
            int par = t & 1;
            f32x4 cs = {csum[0], csum[1], csum[2], csum[3]};
            *(f32x4*)&colacc[par][(w << 2) | lk][lr][0] = cs;
        }
        __syncthreads();                     // orders smem dbuf + colacc publish
        cur ^= 1;
    }
    if (nt > 0 && w == ((nt + 3) & 3)) {     // flush last tile's column partials
        int pcb = (jstart + ((nt - 1) << 4)) << 6;
        if (pcb >= rowBase + 256) {
            int par = (nt - 1) & 1;
            float v = 0.f;
#pragma unroll
            for (int u = 0; u < 16; ++u) v += colacc[par][u][lane & 15][lane >> 4];
            colpart[colpart_off(I) + pcb + lane - ((I + 1) << 8)] = v;
        }
    }
#undef STAGE
#undef BATCH_BODY

    // reduce the 16 col-lanes of each row group, write deterministic row partials
    // (empty lists still write zeros so k_negred can sum all 16 slabs)
#pragma unroll
    for (int r = 0; r < 4; ++r)
#pragma unroll
        for (int q = 0; q < 4; ++q) {
            float v = acc[r][q];
            v += __shfl_xor(v, 1);
            v += __shfl_xor(v, 2);
            v += __shfl_xor(v, 4);
            v += __shfl_xor(v, 8);
            if (lr == 0)
                rowpart[(size_t)s * NROWS + waveRow + r * 16 + lk * 4 + q] = v;
        }
}

// K2b: slice-parallel partial reduction of rowpart+colpart -> negp[8][N].
// 512 blocks; <=10 independent coalesced loads per thread.
__global__ __launch_bounds__(256) void k_negred(const float* __restrict__ rowpart,
                                                const float* __restrict__ colpart,
                                                float* __restrict__ negp) {
    int g = blockIdx.x >> 3;                // row group: rows [256g, 256g+256)
    int z = blockIdx.x & (NSLICE - 1);
    int i = g * 256 + threadIdx.x;
    float a = 0.f;
#pragma unroll
    for (int s = z; s < NSPLIT; s += NSLICE) // 2 iterations
        a += rowpart[(size_t)s * NROWS + i];
    for (int I = z; I < g; I += NSLICE)      // <=8 iterations
        a += colpart[colpart_off(I) + i - ((I + 1) << 8)];
    negp[(size_t)z * NROWS + i] = a;
}

// K3a: per-row loss terms + block partial sums. 64 blocks x 256 threads.
__global__ __launch_bounds__(256) void k_loss1(const float* __restrict__ pos,
                                               const float* __restrict__ negp,
                                               float* __restrict__ bsum) {
    int i = blockIdx.x * 256 + threadIdx.x;
    float neg = 0.f;
#pragma unroll
    for (int z = 0; z < NSLICE; ++z) neg += negp[(size_t)z * NROWS + i];
    neg *= E_M2; // folded (sim - 2.0) shift
    float p = pos[i & (B_ROWS - 1)];
    float Ng = fmaxf((neg - 819.2f * p) * (1.0f / 0.9f), 8192.0f * E_M2);
    float l = fast_log2((p + Ng + 1e-8f) / p) * 0.69314718056f; // = -log(p/(p+Ng+eps))
#pragma unroll
    for (int m = 32; m; m >>= 1) l += __shfl_xor(l, m);
    __shared__ float s4[4];
    int wv = threadIdx.x >> 6;
    if ((threadIdx.x & 63) == 0) s4[wv] = l;
    __syncthreads();
    if (threadIdx.x == 0) bsum[blockIdx.x] = s4[0] + s4[1] + s4[2] + s4[3];
}

// K3b: final reduce of 64 block sums. 1 block, 1 wave.
__global__ void k_loss2(const float* __restrict__ bsum, float* __restrict__ out) {
    float v = bsum[threadIdx.x];
#pragma unroll
    for (int m = 32; m; m >>= 1) v += __shfl_xor(v, m);
    if (threadIdx.x == 0) out[0] = v * (1.0f / (float)NROWS);
}

extern "C" void kernel_launch(void* const* d_in, const int* in_sizes, int n_in,
                              void* d_out, int out_size, void* d_ws, size_t ws_size,
                              hipStream_t stream) {
    const float* zi = (const float*)d_in[0];
    const float* zj = (const float*)d_in[1];
    char* ws = (char*)d_ws;
    unsigned short* reps = (unsigned short*)ws;            // 4 MB
    float* pos = (float*)(ws + 4194304);                   // 32 KB
    float* rowpart = pos + B_ROWS;                         // 16*16384*4 = 1 MB
    float* colpart = rowpart + (size_t)NSPLIT * NROWS;     // 516096*4 ~= 2 MB (triangular)
    float* negp = colpart + 516096;                        // 8*16384*4 = 512 KB
    float* bsum = negp + (size_t)NSLICE * NROWS;           // 256 B
    float* out = (float*)d_out;                            // total ~7.6 MB

    k_norm<<<B_ROWS / 4, 256, 0, stream>>>(zi, zj, (unsigned*)reps, pos);
    k_negsum<<<NBLK, 256, 0, stream>>>(reps, rowpart, colpart);
    k_negred<<<64 * NSLICE, 256, 0, stream>>>(rowpart, colpart, negp);
    k_loss1<<<NROWS / 256, 256, 0, stream>>>(pos, negp, bsum);
    k_loss2<<<1, 64, 0, stream>>>(bsum, out);
}